// Round 10
// baseline (1282.434 us; speedup 1.0000x reference)
//
#include <hip/hip_runtime.h>
#include <hip/hip_bf16.h>

typedef __bf16 bf16_t;
typedef __bf16 bf16x8 __attribute__((ext_vector_type(8)));
typedef float f32x4 __attribute__((ext_vector_type(4)));

#define DI __device__ __forceinline__

static constexpr int TOK = 131072;  // 32 batches * 64*64 tokens
static constexpr int NWIN = 2048;   // 32 * 64 windows

// window-order token t -> source image token (LN1 gather) == proj scatter dest.
DI int src_token(int t) {
  int b = t >> 12;
  int widx = (t >> 6) & 63;
  int n = t & 63;
  int wh = widx >> 3, ww = widx & 7;
  int i = n >> 3, j = n & 7;
  int y = ((wh << 3) + i + 4) & 63;
  int x2 = ((ww << 3) + j + 4) & 63;
  return (b << 12) + (y << 6) + x2;
}

DI f32x4 mfma16(bf16x8 a, bf16x8 b, f32x4 c) {
  return __builtin_amdgcn_mfma_f32_16x16x32_bf16(a, b, c, 0, 0, 0);
}

DI void gload_lds16(const bf16_t* g, bf16_t* l) {
  __builtin_amdgcn_global_load_lds(
      (__attribute__((address_space(1))) void*)const_cast<bf16_t*>(g),
      (__attribute__((address_space(3))) void*)l, 16, 0, 0);
}

// ---------------- weight transpose+convert: w[K][N] f32 -> wt[N][K] bf16 ----
__global__ void wconv_kernel(const float* __restrict__ w, bf16_t* __restrict__ wt,
                             int K, int N) {
  int idx = blockIdx.x * 256 + threadIdx.x;
  if (idx >= N * K) return;
  int n = idx / K, k = idx - n * K;
  wt[idx] = (bf16_t)w[(size_t)k * N + n];
}

// ---------------- LayerNorm (+optional shift/partition gather), f32 -> bf16 --
template <int MAP>
__global__ __launch_bounds__(256)
void ln_kernel(const float* __restrict__ xin, const float* __restrict__ g,
               const float* __restrict__ be, bf16_t* __restrict__ out) {
  int w = threadIdx.x >> 6, l = threadIdx.x & 63;
  int t = blockIdx.x * 4 + w;
  int s = MAP ? src_token(t) : t;
  const float* row = xin + (size_t)s * 384;
  float v[6], s1 = 0.f, s2 = 0.f;
#pragma unroll
  for (int i = 0; i < 6; i++) {
    v[i] = row[l + i * 64];
    s1 += v[i];
    s2 += v[i] * v[i];
  }
#pragma unroll
  for (int o = 32; o; o >>= 1) {
    s1 += __shfl_xor(s1, o);
    s2 += __shfl_xor(s2, o);
  }
  float mean = s1 * (1.f / 384.f);
  float var = s2 * (1.f / 384.f) - mean * mean;
  float rs = rsqrtf(var + 1e-5f);
  bf16_t* orow = out + (size_t)t * 384;
#pragma unroll
  for (int i = 0; i < 6; i++) {
    int idx = l + i * 64;
    orow[idx] = (bf16_t)((v[i] - mean) * rs * g[idx] + be[idx]);
  }
}

// ---------------- GEMM: C[M][N] = A[M][K]*Wt[N][K]^T + bias ------------------
// T3 minimum-2-phase WITHOUT the occupancy tax: BK=32 with A and B interleaved
// into one [128 rows][64 elems] LDS tile (A slots 0-3, B slots 4-7 per 128B
// row) -> a tile-pair is 16KB, so the DOUBLE BUFFER fits the same 32KB as the
// proven single-buffered round-9 kernel (occupancy preserved). 128B rows keep
// the full 8-slot XOR swizzle (slot ^= row&7), conflict-free per the measured
// round-5/6/9 layout (each consecutive-8-lane phase covers all 8 slots once).
// Loop: stage(next buf) BEFORE compute(cur), ONE barrier per K-tile; same
// barrier count as round 9 but loads overlap a full compute phase.
// MODE 0: bf16 out. 1: bf16 gelu(out). 2: f32 scatter(src_token)+resid.
// MODE 3: f32 +resid (resid aliases outf; element owned by one thread).
template <int MODE>
__global__ __launch_bounds__(256, 4)
void gemm_bt(const bf16_t* __restrict__ A, const bf16_t* __restrict__ Wt,
             const float* __restrict__ bias, int K, int ldout, int ncols,
             bf16_t* outb, float* outf, const float* resid) {
  __shared__ __align__(16) bf16_t ABlds[2 * 8192];  // 32 KB
  const int tid = threadIdx.x;
  const int l = tid & 63, w = tid >> 6;
  const int lr = l & 15, lq = l >> 4;
  // XCD-chunked bijective remap (nwg % 8 == 0)
  const int nwg = gridDim.x;
  const int orig = blockIdx.x;
  const int wgid = (orig & 7) * (nwg >> 3) + (orig >> 3);
  const int bn = wgid % ncols, bm = wgid / ncols;
  const int wr = w >> 1, wc = w & 1;

  // Staging: lane owns (row r0 = tid>>3 (+32 per round), slot sl). Inverse
  // swizzle on the GLOBAL side: sl = (tid&7) ^ (r0&7); sl<4 -> A, else -> B.
  const int r0 = tid >> 3;
  const int sl = (tid & 7) ^ (r0 & 7);
  const bf16_t* gsrc =
      (sl < 4 ? A + ((size_t)bm * 128 + r0) * K
              : Wt + ((size_t)bn * 128 + r0) * K) + (sl & 3) * 8;
  const size_t k32 = (size_t)32 * K;  // +32 rows
  bf16_t* ldst = &ABlds[w * 512];     // wave-uniform; HW adds lane*16B

  // K-invariant swizzled read offsets (elems). row&7 == lr&7 for our rows.
  int aoff[4], boff[4];
#pragma unroll
  for (int f = 0; f < 4; f++) {
    int ra = wr * 64 + f * 16 + lr;
    int rb = wc * 64 + f * 16 + lr;
    aoff[f] = ra * 64 + ((lq ^ (lr & 7)) << 3);
    boff[f] = rb * 64 + (((4 + lq) ^ (lr & 7)) << 3);
  }

  f32x4 acc[4][4] = {};

  auto stage = [&](int bb) {  // bb: 0 or 8192 (static)
#pragma unroll
    for (int rr = 0; rr < 4; rr++)
      gload_lds16(gsrc + rr * k32, ldst + bb + rr * 2048);
    gsrc += 32;
  };
  auto compute = [&](int bb) {
    bf16x8 af[4], bfr[4];
#pragma unroll
    for (int f = 0; f < 4; f++) {
      af[f] = *(const bf16x8*)&ABlds[bb + aoff[f]];
      bfr[f] = *(const bf16x8*)&ABlds[bb + boff[f]];
    }
#pragma unroll
    for (int fi = 0; fi < 4; fi++)
#pragma unroll
      for (int fj = 0; fj < 4; fj++)
        acc[fi][fj] = mfma16(af[fi], bfr[fj], acc[fi][fj]);
  };

  const int nt = K >> 5;  // 12 or 48 (always even)
  stage(0);
  __syncthreads();
  for (int t = 0; t + 2 < nt; t += 2) {
    stage(8192);       // tile t+1 -> buf1, overlaps compute(t)
    compute(0);
    __syncthreads();   // buf1 staged; everyone done reading buf0
    stage(0);          // tile t+2 -> buf0
    compute(8192);
    __syncthreads();
  }
  stage(8192);         // last tile
  compute(0);
  __syncthreads();
  compute(8192);

  // ---- epilogue ----
  float bv[4];
#pragma unroll
  for (int fj = 0; fj < 4; fj++)
    bv[fj] = bias[bn * 128 + wc * 64 + fj * 16 + lr];
#pragma unroll
  for (int fi = 0; fi < 4; fi++) {
#pragma unroll
    for (int reg = 0; reg < 4; reg++) {
      int grow = bm * 128 + wr * 64 + fi * 16 + lq * 4 + reg;
      size_t rbase;
      if constexpr (MODE == 2)
        rbase = (size_t)src_token(grow) * ldout;
      else
        rbase = (size_t)grow * ldout;
#pragma unroll
      for (int fj = 0; fj < 4; fj++) {
        int gcol = bn * 128 + wc * 64 + fj * 16 + lr;
        float val = acc[fi][fj][reg] + bv[fj];
        if constexpr (MODE == 0) {
          outb[rbase + gcol] = (bf16_t)val;
        } else if constexpr (MODE == 1) {
          // tanh-form GELU: x * sigmoid(1.59577(x + 0.044715 x^3))
          float z = -1.5957691216f * val * fmaf(0.044715f, val * val, 1.0f);
          val = val / (1.0f + __expf(z));
          outb[rbase + gcol] = (bf16_t)val;
        } else {
          outf[rbase + gcol] = val + resid[rbase + gcol];
        }
      }
    }
  }
}

// ---------------- per-(window, head) attention (staged, swizzled) -----------
__global__ __launch_bounds__(64)
void attn_kernel(const bf16_t* __restrict__ qkv, const float* __restrict__ btab,
                 bf16_t* __restrict__ aout) {
  __shared__ __align__(16) bf16_t Qs[64 * 32];
  __shared__ __align__(16) bf16_t Ks[64 * 32];
  __shared__ __align__(16) bf16_t Vt[32 * 64];
  __shared__ __align__(16) bf16_t Ps[64 * 64];
  const int win = blockIdx.y, h = blockIdx.x;  // h fastest: 12 heads of a
  const int l = threadIdx.x, lr = l & 15, lq = l >> 4;  // window dispatch-adjacent

  {
    const bf16_t* qrow = qkv + ((size_t)win * 64 + l) * 1152 + h * 32;
#pragma unroll
    for (int c = 0; c < 4; c++) {
      *(bf16x8*)&Qs[l * 32 + c * 8] = *(const bf16x8*)&qrow[c * 8];
      *(bf16x8*)&Ks[l * 32 + c * 8] = *(const bf16x8*)&qrow[384 + c * 8];
    }
#pragma unroll
    for (int c = 0; c < 4; c++) {
      bf16x8 tv = *(const bf16x8*)&qrow[768 + c * 8];
#pragma unroll
      for (int e = 0; e < 8; e++) {
        int vr = c * 8 + e;
        Vt[vr * 64 + (l ^ ((vr & 7) << 3))] = tv[e];  // swizzled col
      }
    }
  }
  __syncthreads();

  // S = Q K^T  (64x64, K=32)
  f32x4 sacc[4][4] = {};
  {
    bf16x8 a[4], b[4];
#pragma unroll
    for (int fi = 0; fi < 4; fi++)
      a[fi] = *(const bf16x8*)&Qs[(fi * 16 + lr) * 32 + lq * 8];
#pragma unroll
    for (int fj = 0; fj < 4; fj++)
      b[fj] = *(const bf16x8*)&Ks[(fj * 16 + lr) * 32 + lq * 8];
#pragma unroll
    for (int fi = 0; fi < 4; fi++)
#pragma unroll
      for (int fj = 0; fj < 4; fj++)
        sacc[fi][fj] = mfma16(a[fi], b[fj], sacc[fi][fj]);
  }

  const int widx = win & 63;
  const int wh = widx >> 3, ww = widx & 7;
  const float scale = 0.17677669529663687f;  // 32^-0.5
#pragma unroll
  for (int fi = 0; fi < 4; fi++) {
#pragma unroll
    for (int reg = 0; reg < 4; reg++) {
      int row = fi * 16 + lq * 4 + reg;  // C/D: row=(l>>4)*4+reg (+fi*16)
      int i1 = row >> 3, j1 = row & 7;
      int ly1 = (wh == 7) ? (i1 >= 4 ? 2 : 1) : 0;
      int lx1 = (ww == 7) ? (j1 >= 4 ? 2 : 1) : 0;
      float vals[4], m = -1e30f;
#pragma unroll
      for (int fj = 0; fj < 4; fj++) {
        int col = fj * 16 + lr;  // C/D: col=l&15 (+fj*16)
        int i2 = col >> 3, j2 = col & 7;
        float v = sacc[fi][fj][reg] * scale +
                  btab[((i1 - i2 + 7) * 15 + (j1 - j2 + 7)) * 12 + h];
        int ly2 = (wh == 7) ? (i2 >= 4 ? 2 : 1) : 0;
        int lx2 = (ww == 7) ? (j2 >= 4 ? 2 : 1) : 0;
        if (ly1 != ly2 || lx1 != lx2) v -= 100.f;
        vals[fj] = v;
        m = fmaxf(m, v);
      }
#pragma unroll
      for (int o = 1; o < 16; o <<= 1) m = fmaxf(m, __shfl_xor(m, o));
      float ssum = 0.f;
#pragma unroll
      for (int fj = 0; fj < 4; fj++) {
        vals[fj] = __expf(vals[fj] - m);
        ssum += vals[fj];
      }
#pragma unroll
      for (int o = 1; o < 16; o <<= 1) ssum += __shfl_xor(ssum, o);
      float inv = 1.f / ssum;
      int sw = (row & 7) << 3;
#pragma unroll
      for (int fj = 0; fj < 4; fj++)
        Ps[row * 64 + ((fj * 16 + lr) ^ sw)] = (bf16_t)(vals[fj] * inv);
    }
  }
  __syncthreads();

  // O = P V  (64x32, K=64); swizzled Ps / Vt reads (conflict-free)
  f32x4 oacc[4][2] = {};
#pragma unroll
  for (int kc = 0; kc < 2; kc++) {
    bf16x8 pa[4], vb[2];
#pragma unroll
    for (int fi = 0; fi < 4; fi++) {
      int row = fi * 16 + lr;
      pa[fi] = *(const bf16x8*)&Ps[row * 64 + ((kc * 32 + lq * 8) ^ ((row & 7) << 3))];
    }
#pragma unroll
    for (int fj = 0; fj < 2; fj++) {
      int row = fj * 16 + lr;
      vb[fj] = *(const bf16x8*)&Vt[row * 64 + ((kc * 32 + lq * 8) ^ ((row & 7) << 3))];
    }
#pragma unroll
    for (int fi = 0; fi < 4; fi++)
#pragma unroll
      for (int fj = 0; fj < 2; fj++)
        oacc[fi][fj] = mfma16(pa[fi], vb[fj], oacc[fi][fj]);
  }
#pragma unroll
  for (int fi = 0; fi < 4; fi++)
#pragma unroll
    for (int reg = 0; reg < 4; reg++) {
      int row = fi * 16 + lq * 4 + reg;
      size_t rb = ((size_t)win * 64 + row) * 384 + h * 32;
#pragma unroll
      for (int fj = 0; fj < 2; fj++)
        aout[rb + fj * 16 + lr] = (bf16_t)oacc[fi][fj][reg];
    }
}

// ---------------------------------------------------------------------------
extern "C" void kernel_launch(void* const* d_in, const int* in_sizes, int n_in,
                              void* d_out, int out_size, void* d_ws, size_t ws_size,
                              hipStream_t stream) {
  (void)in_sizes; (void)n_in; (void)out_size; (void)ws_size;
  const float* x      = (const float*)d_in[0];
  const float* gamma1 = (const float*)d_in[1];
  const float* beta1  = (const float*)d_in[2];
  const float* w_qkv  = (const float*)d_in[3];
  const float* b_qkv  = (const float*)d_in[4];
  const float* btab   = (const float*)d_in[5];
  const float* w_proj = (const float*)d_in[6];
  const float* b_proj = (const float*)d_in[7];
  const float* gamma2 = (const float*)d_in[8];
  const float* beta2  = (const float*)d_in[9];
  const float* w_fc1  = (const float*)d_in[10];
  const float* b_fc1  = (const float*)d_in[11];
  const float* w_fc2  = (const float*)d_in[12];
  const float* b_fc2  = (const float*)d_in[13];
  float* out = (float*)d_out;

  char* ws = (char*)d_ws;
  size_t off = 0;
  auto alloc = [&](size_t bytes) {
    void* p = ws + off;
    off += (bytes + 255) & ~(size_t)255;
    return p;
  };
  bf16_t* wqkvT  = (bf16_t*)alloc((size_t)1152 * 384 * 2);
  bf16_t* wprojT = (bf16_t*)alloc((size_t)384 * 384 * 2);
  bf16_t* wfc1T  = (bf16_t*)alloc((size_t)1536 * 384 * 2);
  bf16_t* wfc2T  = (bf16_t*)alloc((size_t)384 * 1536 * 2);
  // qkv rows [TOK][1152] alias mlp hidden [TOK][1536]; lifetimes disjoint.
  char* big = (char*)alloc((size_t)TOK * 1536 * 2);
  bf16_t* bufA = (bf16_t*)big;  // qkv rows
  bf16_t* bufH = (bf16_t*)big;  // mlp hidden
  bf16_t* bufB = (bf16_t*)alloc((size_t)TOK * 384 * 2);  // ln1/attn/ln2 rows

  wconv_kernel<<<(1152 * 384 + 255) / 256, 256, 0, stream>>>(w_qkv, wqkvT, 384, 1152);
  wconv_kernel<<<(384 * 384 + 255) / 256, 256, 0, stream>>>(w_proj, wprojT, 384, 384);
  wconv_kernel<<<(384 * 1536 + 255) / 256, 256, 0, stream>>>(w_fc1, wfc1T, 384, 1536);
  wconv_kernel<<<(1536 * 384 + 255) / 256, 256, 0, stream>>>(w_fc2, wfc2T, 1536, 384);

  // LN1 + roll + window partition -> bufB [131072][384] bf16
  ln_kernel<1><<<TOK / 4, 256, 0, stream>>>(x, gamma1, beta1, bufB);
  // QKV: [131072,384] x [384,1152] -> bufA bf16   (grid 9*1024, %8==0)
  gemm_bt<0><<<9 * (TOK / 128), 256, 0, stream>>>(
      bufB, wqkvT, b_qkv, 384, 1152, 9, bufA, nullptr, nullptr);
  // windowed attention -> bufB [131072][384] bf16
  attn_kernel<<<dim3(12, NWIN), 64, 0, stream>>>(bufA, btab, bufB);
  // proj + un-roll scatter + residual(x) -> out (x1, f32)  (grid 3*1024)
  gemm_bt<2><<<3 * (TOK / 128), 256, 0, stream>>>(
      bufB, wprojT, b_proj, 384, 384, 3, nullptr, out, x);
  // LN2 -> bufB bf16
  ln_kernel<0><<<TOK / 4, 256, 0, stream>>>(out, gamma2, beta2, bufB);
  // FC1 + fast GELU -> bufH [131072][1536] bf16  (grid 12*1024)
  gemm_bt<1><<<12 * (TOK / 128), 256, 0, stream>>>(
      bufB, wfc1T, b_fc1, 384, 1536, 12, bufH, nullptr, nullptr);
  // FC2 + residual(out, in-place) -> out  (grid 3*1024)
  gemm_bt<3><<<3 * (TOK / 128), 256, 0, stream>>>(
      bufH, wfc2T, b_fc2, 1536, 384, 3, nullptr, out, out);
}